// Round 5
// baseline (268.190 us; speedup 1.0000x reference)
//
#include <hip/hip_runtime.h>

// SigJoin (Chen's identity), D=8, M=6, BATCH=128.
// z_K[j] = x_K[j] + y[j&7] * S,  S = sum_{i=0}^{K-1} x_i[j>>3^(K-i)] * Q_i / (K-i)!
// (x_0 = 1). Level start offsets (element space): 0, 8, 72, 584, 4680, 37448.
//
// R2 lesson (rocprof): partial-line nt stores (128B lane stride) -> 3.4x write
// amplification, 430 us. Fixed with wave-contiguous float4 stores -> ~90 us.
// R4 lesson: kernel now below the 91 us fill dispatches; ~55% of copy ceiling.
// This version: 4 chunks per thread (c, c+256, c+512, c+768) -> 4 independent
// 16B load/store streams per lane in flight, every instruction still covers
// 1KB wave-contiguous (16 full 64B lines). Grid 37504 -> 9472 blocks.

#define SIGLEN 299592
#define NCHUNK (SIGLEN / 4)   // 74898 float4 chunks per row (exact)
#define CPT 4                 // chunks per thread

typedef float v4f __attribute__((ext_vector_type(4)));

__device__ constexpr float INV_FACT[8] = {1.f, 1.f, 0.5f, 1.f/6.f, 1.f/24.f,
                                          1.f/120.f, 1.f/720.f, 1.f/5040.f};
__device__ constexpr int LOFF[7] = {0, 0, 8, 72, 584, 4680, 37448};

// Prefix chain for the group containing element col at level K.
template<int K>
__device__ __forceinline__ float prefix_S(const float* __restrict__ xrow,
                                          const float* sy, int col) {
    int tt = (col - LOFF[K]) >> 3;   // prefix index at level K-1
    float S = 0.f, Q = 1.f;
#pragma unroll
    for (int i = K - 1; i >= 1; --i) {
        S += xrow[LOFF[i] + tt] * (INV_FACT[K - i] * Q);
        Q *= sy[tt & 7];
        tt >>= 3;
    }
    S += Q * INV_FACT[K];            // e_K term (x_0 = 1)
    return S;
}

__device__ __forceinline__ float S_of(const float* __restrict__ xrow,
                                      const float* sy, int col) {
    if      (col >= 37448) return prefix_S<6>(xrow, sy, col);
    else if (col >=  4680) return prefix_S<5>(xrow, sy, col);
    else if (col >=   584) return prefix_S<4>(xrow, sy, col);
    else if (col >=    72) return prefix_S<3>(xrow, sy, col);
    else if (col >=     8) return prefix_S<2>(xrow, sy, col);
    else                   return 1.f;   // level 1: z = x + y
}

__global__ __launch_bounds__(256) void sigjoin_kernel(
    const float* __restrict__ x, const float* __restrict__ y,
    float* __restrict__ out)
{
    __shared__ float sy[8];
    const int row = blockIdx.y;
    const int tid = threadIdx.x;
    if (tid < 8) sy[tid] = y[row * 8 + tid];
    __syncthreads();

    const float* __restrict__ xrow = x   + (size_t)row * SIGLEN;
    float* __restrict__       orow = out + (size_t)row * SIGLEN;

    const int base = blockIdx.x * (256 * CPT) + tid;   // chunk index of stream 0

    // Issue all main loads first: 4 independent 1KB wave-contiguous reads.
    v4f xa[CPT];
    bool act[CPT];
#pragma unroll
    for (int i = 0; i < CPT; ++i) {
        const int c = base + i * 256;
        act[i] = (c < NCHUNK);
        if (act[i]) xa[i] = *(const v4f*)(xrow + c * 4);
    }

    // Prefix chains (cached loads, tiny footprint) + stores.
#pragma unroll
    for (int i = 0; i < CPT; ++i) {
        if (!act[i]) continue;
        const int col = (base + i * 256) * 4;
        const float S = S_of(xrow, sy, col);
        const v4f yh = *(const v4f*)(&sy[col & 4]);    // digits 0-3 or 4-7
        const v4f za = xa[i] + S * yh;
        __builtin_nontemporal_store(za, (v4f*)(orow + col));
    }
}

extern "C" void kernel_launch(void* const* d_in, const int* in_sizes, int n_in,
                              void* d_out, int out_size, void* d_ws, size_t ws_size,
                              hipStream_t stream) {
    const float* x = (const float*)d_in[0];
    const float* y = (const float*)d_in[1];
    float* out = (float*)d_out;

    const int bx = (NCHUNK + 256 * CPT - 1) / (256 * CPT);   // 74 blocks per row
    dim3 grid(bx, 128, 1);
    dim3 block(256, 1, 1);
    hipLaunchKernelGGL(sigjoin_kernel, grid, block, 0, stream, x, y, out);
}

// Round 6
// 266.408 us; speedup vs baseline: 1.0067x; 1.0067x over previous
//
#include <hip/hip_runtime.h>

// SigJoin (Chen's identity), D=8, M=6, BATCH=128.
// z_K[j] = x_K[j] + y[j&7] * S,  S = sum_{i=0}^{K-1} x_i[j>>3^(K-i)] * Q_i / (K-i)!
// (x_0 = 1). Level start offsets (element space): 0, 8, 72, 584, 4680, 37448.
//
// R2 lesson: partial-line nt stores -> 3.4x write amplification (521 MB), 430 us.
// R5 lesson: full-line wave-contiguous stores -> WRITE exactly ideal (152 MB),
//   ~95 us, but only 2.5 TB/s vs 6.7 TB/s that fillBuffer sustains here; VALU,
//   occupancy, MLP all ruled out (CPT=1 vs 4 indistinguishable).
// R6 A/B (this version): ONLY change vs R5 = nontemporal stores -> plain cached
//   stores. Theory: nt (no-allocate/evict-first) store path caps per-CU write
//   throughput; plain stores use the same path as the 6.7 TB/s fill kernel.

#define SIGLEN 299592
#define NCHUNK (SIGLEN / 4)   // 74898 float4 chunks per row (exact)
#define CPT 4                 // chunks per thread

typedef float v4f __attribute__((ext_vector_type(4)));

__device__ constexpr float INV_FACT[8] = {1.f, 1.f, 0.5f, 1.f/6.f, 1.f/24.f,
                                          1.f/120.f, 1.f/720.f, 1.f/5040.f};
__device__ constexpr int LOFF[7] = {0, 0, 8, 72, 584, 4680, 37448};

// Prefix chain for the group containing element col at level K.
template<int K>
__device__ __forceinline__ float prefix_S(const float* __restrict__ xrow,
                                          const float* sy, int col) {
    int tt = (col - LOFF[K]) >> 3;   // prefix index at level K-1
    float S = 0.f, Q = 1.f;
#pragma unroll
    for (int i = K - 1; i >= 1; --i) {
        S += xrow[LOFF[i] + tt] * (INV_FACT[K - i] * Q);
        Q *= sy[tt & 7];
        tt >>= 3;
    }
    S += Q * INV_FACT[K];            // e_K term (x_0 = 1)
    return S;
}

__device__ __forceinline__ float S_of(const float* __restrict__ xrow,
                                      const float* sy, int col) {
    if      (col >= 37448) return prefix_S<6>(xrow, sy, col);
    else if (col >=  4680) return prefix_S<5>(xrow, sy, col);
    else if (col >=   584) return prefix_S<4>(xrow, sy, col);
    else if (col >=    72) return prefix_S<3>(xrow, sy, col);
    else if (col >=     8) return prefix_S<2>(xrow, sy, col);
    else                   return 1.f;   // level 1: z = x + y
}

__global__ __launch_bounds__(256) void sigjoin_kernel(
    const float* __restrict__ x, const float* __restrict__ y,
    float* __restrict__ out)
{
    __shared__ float sy[8];
    const int row = blockIdx.y;
    const int tid = threadIdx.x;
    if (tid < 8) sy[tid] = y[row * 8 + tid];
    __syncthreads();

    const float* __restrict__ xrow = x   + (size_t)row * SIGLEN;
    float* __restrict__       orow = out + (size_t)row * SIGLEN;

    const int base = blockIdx.x * (256 * CPT) + tid;   // chunk index of stream 0

    // Issue all main loads first: 4 independent 1KB wave-contiguous reads.
    v4f xa[CPT];
    bool act[CPT];
#pragma unroll
    for (int i = 0; i < CPT; ++i) {
        const int c = base + i * 256;
        act[i] = (c < NCHUNK);
        if (act[i]) xa[i] = *(const v4f*)(xrow + c * 4);
    }

    // Prefix chains (cached loads, tiny footprint) + stores.
#pragma unroll
    for (int i = 0; i < CPT; ++i) {
        if (!act[i]) continue;
        const int col = (base + i * 256) * 4;
        const float S = S_of(xrow, sy, col);
        const v4f yh = *(const v4f*)(&sy[col & 4]);    // digits 0-3 or 4-7
        const v4f za = xa[i] + S * yh;
        *(v4f*)(orow + col) = za;                      // PLAIN cached store (A/B vs R5)
    }
}

extern "C" void kernel_launch(void* const* d_in, const int* in_sizes, int n_in,
                              void* d_out, int out_size, void* d_ws, size_t ws_size,
                              hipStream_t stream) {
    const float* x = (const float*)d_in[0];
    const float* y = (const float*)d_in[1];
    float* out = (float*)d_out;

    const int bx = (NCHUNK + 256 * CPT - 1) / (256 * CPT);   // 74 blocks per row
    dim3 grid(bx, 128, 1);
    dim3 block(256, 1, 1);
    hipLaunchKernelGGL(sigjoin_kernel, grid, block, 0, stream, x, y, out);
}